// Round 14
// baseline (2026.465 us; speedup 1.0000x reference)
//
#include <hip/hip_runtime.h>

// LSTM BS=512, T=2048, IN=64, HS=128.
// 512 blocks x 1 batch row, 8 waves, __launch_bounds__(512,4) -> 2 blocks/CU:
// two independent recurrences per CU at uncorrelated phases fill each other's
// latency bubbles (MFMA pipe of one overlaps activation/barrier of the other).
// ROWS=1 kills the gate redistribution: lanes 0-15 of each wave hold all 4
// gates of their column in acc[n][0] -> direct in-register cell update.
// Chunk GEMM (Z = x@W + bias, CH=32, 2 dense 16-row m-tiles) reads x from an
// LDS tile staged during the previous chunk's scan (T14 split).

#define T_STEPS 2048
#define IN_DIM 64
#define HS 128
#define NG 512
#define NBLK 512
#define NTHR 512
#define CH 32
#define NCH (T_STEPS / CH)
#define ZSTR 520   // shorts per tl row of Zc (512 + 8 pad -> bank rotate)
#define XSTR 68    // floats per tl row of Xl (64 + 4 pad)

typedef float f32x4 __attribute__((ext_vector_type(4)));
typedef short s16x8 __attribute__((ext_vector_type(8)));

__device__ __forceinline__ unsigned f2bf(float f) {
  unsigned u = __float_as_uint(f);
  return (u + 0x7fffu + ((u >> 16) & 1u)) >> 16;  // RNE
}
__device__ __forceinline__ float rcpf(float x) { return __builtin_amdgcn_rcpf(x); }
__device__ __forceinline__ float sigm(float x) { return rcpf(1.0f + __expf(-x)); }
__device__ __forceinline__ float tanhfast(float x) {
  return 1.0f - 2.0f * rcpf(__expf(2.0f * x) + 1.0f);  // exact at +-inf
}

__global__ __launch_bounds__(NTHR, 4)
void lstm1(const float* __restrict__ X, const float* __restrict__ W,
           const float* __restrict__ U, const float* __restrict__ B,
           const float* __restrict__ LW, const float* __restrict__ LB,
           float* __restrict__ OUT) {
  __shared__ __align__(16) short Zc[CH * ZSTR];   // 33.3 KB gates (bf16)
  __shared__ __align__(16) float Xl[CH * XSTR];   // 8.7 KB x-tile
  __shared__ __align__(16) short Hb[2][136];      // h double buffer (1 row)
  __shared__ float Ys[HS];

  const int tid  = threadIdx.x;
  const int lane = tid & 63;
  const int w    = tid >> 6;
  const int lrow = lane & 15;
  const int lg   = lane >> 4;
  const int row  = blockIdx.x;          // batch row
  const int col  = w * 16 + lrow;       // gate column this lane owns

  // ---- persistent weight fragments: wave w owns col p = n*128 + col ----
  // B-frag (mfma_f32_16x16x32_bf16): B[k][p], k = kt*32 + 8*lg + j
  s16x8 bfrU[4][4];   // K=128 (U)
  s16x8 bfrW[4][2];   // K=64  (W) -- cold between chunks (spill candidate, ok)
  float biasg[4];
#pragma unroll
  for (int n = 0; n < 4; ++n) {
    const int p = n * HS + col;
#pragma unroll
    for (int kt = 0; kt < 4; ++kt)
#pragma unroll
      for (int j = 0; j < 8; ++j)
        bfrU[n][kt][j] = (short)f2bf(U[(kt * 32 + (lg << 3) + j) * NG + p]);
#pragma unroll
    for (int kt = 0; kt < 2; ++kt)
#pragma unroll
      for (int j = 0; j < 8; ++j)
        bfrW[n][kt][j] = (short)f2bf(W[(kt * 32 + (lg << 3) + j) * NG + p]);
    biasg[n] = B[p];
  }

  // ---- x staging (T14 split): one f32x4 per thread per chunk ----
  const int stl = tid >> 4;             // t-local 0..31
  const int sk  = (tid & 15) * 4;       // feature 0..60
  const float* xsrc = X + ((long)row * T_STEPS + stl) * IN_DIM + sk;
  f32x4 sx;
  auto stage_load  = [&](int cc) { sx = *(const f32x4*)(xsrc + (long)cc * CH * IN_DIM); };
  auto stage_write = [&]() { *(f32x4*)&Xl[stl * XSTR + sk] = sx; };

  stage_load(0);
  stage_write();
  for (int i = tid; i < 2 * 136; i += NTHR) ((short*)Hb)[i] = 0;  // h(0) = 0

  float creg = 0.f, hreg = 0.f;
  const bool act = (lane < 16);
  __syncthreads();

#pragma unroll 1
  for (int c = 0; c < NCH; ++c) {
    // ===== chunk GEMM: Zc = x@W + bias, 2 dense m-tiles (16 timesteps each)
#pragma unroll
    for (int mt = 0; mt < 2; ++mt) {
      const int tb = (mt * 16 + lrow) * XSTR;
      const f32x4 x0 = *(const f32x4*)&Xl[tb + (lg << 3)];
      const f32x4 x1 = *(const f32x4*)&Xl[tb + (lg << 3) + 4];
      const f32x4 x2 = *(const f32x4*)&Xl[tb + 32 + (lg << 3)];
      const f32x4 x3 = *(const f32x4*)&Xl[tb + 32 + (lg << 3) + 4];
      s16x8 a0, a1;
#pragma unroll
      for (int j = 0; j < 4; ++j) {
        a0[j] = (short)f2bf(x0[j]); a0[4 + j] = (short)f2bf(x1[j]);
        a1[j] = (short)f2bf(x2[j]); a1[4 + j] = (short)f2bf(x3[j]);
      }
      f32x4 ac[4];
#pragma unroll
      for (int n = 0; n < 4; ++n) {
        ac[n][0] = biasg[n]; ac[n][1] = biasg[n];
        ac[n][2] = biasg[n]; ac[n][3] = biasg[n];
      }
#pragma unroll
      for (int n = 0; n < 4; ++n)
        ac[n] = __builtin_amdgcn_mfma_f32_16x16x32_bf16(a0, bfrW[n][0], ac[n], 0, 0, 0);
#pragma unroll
      for (int n = 0; n < 4; ++n)
        ac[n] = __builtin_amdgcn_mfma_f32_16x16x32_bf16(a1, bfrW[n][1], ac[n], 0, 0, 0);
      // D row d = 4lg+rr -> tl = mt*16 + d ; lane writes its col's 4 gates (8B)
#pragma unroll
      for (int rr = 0; rr < 4; ++rr) {
        const int tlz = mt * 16 + 4 * lg + rr;
        uint2 u;
        u.x = f2bf(ac[0][rr]) | (f2bf(ac[1][rr]) << 16);
        u.y = f2bf(ac[2][rr]) | (f2bf(ac[3][rr]) << 16);
        *(uint2*)&Zc[tlz * ZSTR + col * 4] = u;
      }
    }
    __syncthreads();                       // Zc ready; Xl consumed
    stage_load((c + 1 < NCH) ? c + 1 : c); // issue next chunk's x loads

    // ===== 32 scan steps ===================================================
#pragma unroll 1
    for (int tl = 0; tl < CH; ++tl) {
      const int t = c * CH + tl;

      const uint2 zu = *(const uint2*)&Zc[tl * ZSTR + col * 4];
      f32x4 acc[4];
#pragma unroll
      for (int n = 0; n < 4; ++n) acc[n] = (f32x4){0.f, 0.f, 0.f, 0.f};
      acc[0][0] = act ? __int_as_float(zu.x << 16)          : 0.f;
      acc[1][0] = act ? __int_as_float(zu.x & 0xffff0000u)  : 0.f;
      acc[2][0] = act ? __int_as_float(zu.y << 16)          : 0.f;
      acc[3][0] = act ? __int_as_float(zu.y & 0xffff0000u)  : 0.f;

      // A-frag: all lanes broadcast-read row-0 h (A rows 1..15 become
      // duplicates of row 0 -> only D row 0 is read, so harmless).
      __builtin_amdgcn_s_setprio(1);
#pragma unroll
      for (int kt = 0; kt < 4; ++kt) {
        const s16x8 a = *(const s16x8*)&Hb[t & 1][kt * 32 + (lg << 3)];
        acc[0] = __builtin_amdgcn_mfma_f32_16x16x32_bf16(a, bfrU[0][kt], acc[0], 0, 0, 0);
        acc[2] = __builtin_amdgcn_mfma_f32_16x16x32_bf16(a, bfrU[2][kt], acc[2], 0, 0, 0);
        acc[1] = __builtin_amdgcn_mfma_f32_16x16x32_bf16(a, bfrU[1][kt], acc[1], 0, 0, 0);
        acc[3] = __builtin_amdgcn_mfma_f32_16x16x32_bf16(a, bfrU[3][kt], acc[3], 0, 0, 0);
      }
      __builtin_amdgcn_s_setprio(0);

      if (tl == 4) stage_write();          // x arrived long ago; Xl free

      if (act) {                           // one full cell update per lane
        const float iv = sigm(acc[0][0]);
        const float fv = sigm(acc[1][0]);
        const float gv = tanhfast(acc[2][0]);
        const float ov = sigm(acc[3][0]);
        creg = fv * creg + iv * gv;
        hreg = ov * tanhfast(creg);
        if (t < T_STEPS - 1) {
          Hb[(t + 1) & 1][col] = (short)f2bf(hreg);
        } else {
          OUT[512 + row * HS + col]   = hreg;   // h_t
          OUT[66048 + row * HS + col] = creg;   // c_t
          Ys[col] = LW[col] * hreg;             // y partial
        }
      }
      __syncthreads();
    }
  }

  // ---- y = h @ linear_w.T + b ----
  if (w == 0) {
    float v = Ys[lane] + Ys[64 + lane];
#pragma unroll
    for (int off = 32; off > 0; off >>= 1) v += __shfl_down(v, off);
    if (lane == 0) OUT[row] = v + LB[0];
  }
}

extern "C" void kernel_launch(void* const* d_in, const int* in_sizes, int n_in,
                              void* d_out, int out_size, void* d_ws, size_t ws_size,
                              hipStream_t stream) {
  const float* X  = (const float*)d_in[0];
  const float* W  = (const float*)d_in[1];
  const float* U  = (const float*)d_in[2];
  const float* B  = (const float*)d_in[3];
  const float* LW = (const float*)d_in[4];
  const float* LB = (const float*)d_in[5];
  lstm1<<<dim3(NBLK), dim3(NTHR), 0, stream>>>(X, W, U, B, LW, LB, (float*)d_out);
}

// Round 15
// 1055.644 us; speedup vs baseline: 1.9196x; 1.9196x over previous
//
#include <hip/hip_runtime.h>

// LSTM BS=512, T=2048, IN=64, HS=128.  Single fused persistent kernel.
// R13 structure (best, 1332us): 256 blocks x 2 rows, 8 waves; chunk GEMM
// (Z = x@W + bias, bf16) from an LDS-staged x tile (T14 split); scan does
// only the U*h product per step.
// R15 change: U*h switches bf16 -> int8 MFMA (mfma_i32_16x16x64_i8, K=64):
// 16 -> 8 MFMAs/wave/step, chain depth 4 -> 2. U quantized per-column
// (su = max|U[:,c]|/127); h quantized to i8 (exact range (-1,1)); gates
// dequantized in the epilogue: v = acc_i32 * (su/127) + Z.

#define T_STEPS 2048
#define IN_DIM 64
#define HS 128
#define NG 512
#define ROWS 2
#define NBLK 256
#define NTHR 512
#define CH 32
#define NCH (T_STEPS / CH)
#define HROW 144   // bytes per h row (128 + 16 pad, 16B aligned)

typedef float f32x4 __attribute__((ext_vector_type(4)));
typedef short s16x8 __attribute__((ext_vector_type(8)));
typedef int   i32x4 __attribute__((ext_vector_type(4)));

__device__ __forceinline__ unsigned f2bf(float f) {
  unsigned u = __float_as_uint(f);
  return (u + 0x7fffu + ((u >> 16) & 1u)) >> 16;  // RNE
}
__device__ __forceinline__ float bf2f(unsigned short s) {
  return __int_as_float(((int)s) << 16);
}
__device__ __forceinline__ float rcpf(float x) { return __builtin_amdgcn_rcpf(x); }
__device__ __forceinline__ float sigm(float x) { return rcpf(1.0f + __expf(-x)); }
__device__ __forceinline__ float tanhfast(float x) {
  return 1.0f - 2.0f * rcpf(__expf(2.0f * x) + 1.0f);  // exact at +-inf
}
// Xl float-index swizzle: XOR t' (bits 7..9) into the 8-float granule bits
__device__ __forceinline__ int xswz(int f) { return f ^ (((f >> 7) & 7) << 3); }

__global__ __launch_bounds__(NTHR, 1)
void lstm_fused(const float* __restrict__ X, const float* __restrict__ W,
                const float* __restrict__ U, const float* __restrict__ B,
                const float* __restrict__ LW, const float* __restrict__ LB,
                float* __restrict__ OUT) {
  __shared__ __align__(16) short Zc[CH * 128 * 8];        // 64 KB gates bf16
  __shared__ __align__(16) float Xl[4096];                // 16 KB x-tile
  __shared__ __align__(16) unsigned char Hq[2][ROWS * HROW];  // h as i8
  __shared__ float Ys[256];
  __shared__ float Ps[8];

  const int tid  = threadIdx.x;
  const int lane = tid & 63;
  const int w    = tid >> 6;
  const int blk  = blockIdx.x;
  const int lrow = lane & 15;
  const int lg   = lane >> 4;
  const int col8 = (w * 16 + lrow) * 8;   // Zc column offset (shorts)

  // ---- U: per-column int8 quantization; wave w owns col p = n*128+16w+lrow
  // B-frag (mfma_i32_16x16x64_i8): B[k][p], k = kt*64 + 16*(lane>>4) + j
  i32x4 bUq[4][2];
  float scl[4];
  s16x8 bfrW[4][2];
  float biasg[4];
#pragma unroll
  for (int n = 0; n < 4; ++n) {
    const int p = n * HS + w * 16 + lrow;
    float m = 1e-8f;
    for (int k = 0; k < HS; ++k) m = fmaxf(m, fabsf(U[k * NG + p]));
    const float su = m / 127.f;
    const float rsu = 127.f / m;
    scl[n] = su * (1.f / 127.f);
#pragma unroll
    for (int kt = 0; kt < 2; ++kt) {
      int vq[4] = {0, 0, 0, 0};
      for (int j = 0; j < 16; ++j) {
        const int k = kt * 64 + (lg << 4) + j;
        int q = (int)rintf(U[k * NG + p] * rsu);
        q = q < -127 ? -127 : (q > 127 ? 127 : q);
        vq[j >> 2] |= (q & 0xff) << ((j & 3) * 8);
      }
      bUq[n][kt] = (i32x4){vq[0], vq[1], vq[2], vq[3]};
    }
#pragma unroll
    for (int kt = 0; kt < 2; ++kt)
#pragma unroll
      for (int j = 0; j < 8; ++j)
        bfrW[n][kt][j] = (short)f2bf(W[(kt * 32 + (lg << 3) + j) * NG + p]);
    biasg[n] = B[p];
  }

  // ---- x staging (T14 split): waves 0..3 own m-tile w of the chunk ----
  f32x4 sx0, sx1, sx2, sx3;
  auto stage_load = [&](int cc) {
    if (w < 4) {
#pragma unroll
      for (int q = 0; q < 4; ++q) {
        const int f   = w * 1024 + q * 256 + lane * 4;
        const int tlc = f >> 7;
        const int row = (f >> 6) & 1;
        const int k   = f & 63;
        const f32x4 v = *(const f32x4*)(
            X + ((long)(blk * ROWS + row) * T_STEPS + (long)cc * CH + tlc) * IN_DIM + k);
        if (q == 0) sx0 = v; else if (q == 1) sx1 = v;
        else if (q == 2) sx2 = v; else sx3 = v;
      }
    }
  };
  auto stage_write = [&]() {
    if (w < 4) {
#pragma unroll
      for (int q = 0; q < 4; ++q) {
        const int f = w * 1024 + q * 256 + lane * 4;
        const f32x4 v = (q == 0) ? sx0 : (q == 1) ? sx1 : (q == 2) ? sx2 : sx3;
        *(f32x4*)&Xl[xswz(f)] = v;
      }
    }
  };

  stage_load(0);
  stage_write();
  for (int i = tid; i < 2 * ROWS * HROW; i += NTHR) ((unsigned char*)Hq)[i] = 0;

  i32x4 afr[2];
  const i32x4 izer = {0, 0, 0, 0};
  afr[0] = izer; afr[1] = izer;   // h(0) = 0

  float creg = 0.f, hreg = 0.f;
  __syncthreads();

#pragma unroll 1
  for (int c = 0; c < NCH; ++c) {
    // ===== chunk GEMM: Zc = x@W + bias, x from LDS (bf16, unchanged) ======
#pragma unroll
    for (int mt = 0; mt < 4; ++mt) {
      const int fb = mt * 1024 + (lrow >> 1) * 128 + (lrow & 1) * 64;
      const int f0 = xswz(fb + 8 * lg);
      const int f1 = xswz(fb + 32 + 8 * lg);
      const f32x4 x0 = *(const f32x4*)&Xl[f0];
      const f32x4 x1 = *(const f32x4*)&Xl[f0 + 4];
      const f32x4 x2 = *(const f32x4*)&Xl[f1];
      const f32x4 x3 = *(const f32x4*)&Xl[f1 + 4];
      s16x8 a0, a1;
#pragma unroll
      for (int j = 0; j < 4; ++j) {
        a0[j] = (short)f2bf(x0[j]); a0[4 + j] = (short)f2bf(x1[j]);
        a1[j] = (short)f2bf(x2[j]); a1[4 + j] = (short)f2bf(x3[j]);
      }
      f32x4 ac[4];
#pragma unroll
      for (int n = 0; n < 4; ++n) {
        ac[n][0] = biasg[n]; ac[n][1] = biasg[n];
        ac[n][2] = biasg[n]; ac[n][3] = biasg[n];
      }
#pragma unroll
      for (int n = 0; n < 4; ++n)
        ac[n] = __builtin_amdgcn_mfma_f32_16x16x32_bf16(a0, bfrW[n][0], ac[n], 0, 0, 0);
#pragma unroll
      for (int n = 0; n < 4; ++n)
        ac[n] = __builtin_amdgcn_mfma_f32_16x16x32_bf16(a1, bfrW[n][1], ac[n], 0, 0, 0);
      s16x8 z0, z1;
#pragma unroll
      for (int n = 0; n < 4; ++n) {
        z0[n] = (short)f2bf(ac[n][0]); z0[4 + n] = (short)f2bf(ac[n][1]);
        z1[n] = (short)f2bf(ac[n][2]); z1[4 + n] = (short)f2bf(ac[n][3]);
      }
      const int tl0 = mt * 8 + 2 * lg;
      *(s16x8*)&Zc[tl0 * 1024 + col8]       = z0;
      *(s16x8*)&Zc[(tl0 + 1) * 1024 + col8] = z1;
    }
    __syncthreads();
    stage_load((c + 1 < NCH) ? c + 1 : c);

    // ===== 32 scan steps: i8 MFMA (K=64 x2), dequant+Z in epilogue ========
#pragma unroll 1
    for (int tl = 0; tl < CH; ++tl) {
      const int t = c * CH + tl;
      const s16x8 zc = *(const s16x8*)&Zc[tl * 1024 + col8];

      i32x4 acc[4];
#pragma unroll
      for (int n = 0; n < 4; ++n) acc[n] = izer;

      __builtin_amdgcn_s_setprio(1);
#pragma unroll
      for (int kt = 0; kt < 2; ++kt) {
        acc[0] = __builtin_amdgcn_mfma_i32_16x16x64_i8(afr[kt], bUq[0][kt], acc[0], 0, 0, 0);
        acc[2] = __builtin_amdgcn_mfma_i32_16x16x64_i8(afr[kt], bUq[2][kt], acc[2], 0, 0, 0);
        acc[1] = __builtin_amdgcn_mfma_i32_16x16x64_i8(afr[kt], bUq[1][kt], acc[1], 0, 0, 0);
        acc[3] = __builtin_amdgcn_mfma_i32_16x16x64_i8(afr[kt], bUq[3][kt], acc[3], 0, 0, 0);
      }
      __builtin_amdgcn_s_setprio(0);

      if (tl == 4) stage_write();

      // row1 (reg1) -> lanes 16..31 via xor16 swizzle; dequant + Z; activate
      const int hi16 = lane & 16;
      const int q0 = __builtin_amdgcn_ds_swizzle(acc[0][1], 0x401F);
      const int q2 = __builtin_amdgcn_ds_swizzle(acc[2][1], 0x401F);
      const float v0 = (float)(hi16 ? q0 : acc[0][0]) * scl[0]
                     + bf2f((unsigned short)(hi16 ? zc[4] : zc[0]));
      const float v2 = (float)(hi16 ? q2 : acc[2][0]) * scl[2]
                     + bf2f((unsigned short)(hi16 ? zc[6] : zc[2]));
      const float iv = sigm(v0), gv = tanhfast(v2);
      const float pg = iv * gv;
      const int q1 = __builtin_amdgcn_ds_swizzle(acc[1][1], 0x401F);
      const int q3 = __builtin_amdgcn_ds_swizzle(acc[3][1], 0x401F);
      const float v1 = (float)(hi16 ? q1 : acc[1][0]) * scl[1]
                     + bf2f((unsigned short)(hi16 ? zc[5] : zc[1]));
      const float v3 = (float)(hi16 ? q3 : acc[3][0]) * scl[3]
                     + bf2f((unsigned short)(hi16 ? zc[7] : zc[3]));
      const float fv = sigm(v1), ov = sigm(v3);
      creg = fv * creg + pg;
      hreg = ov * tanhfast(creg);

      if (lane < 32) {
        const int colc = w * 16 + lrow;
        const int r    = lg & 1;
        if (t < T_STEPS - 1) {
          const int hq = (int)rintf(hreg * 127.f);
          Hq[(t + 1) & 1][r * HROW + colc] = (unsigned char)hq;
        } else {
          const int row = blk * ROWS + r;
          OUT[512 + row * HS + colc]   = hreg;   // h_t
          OUT[66048 + row * HS + colc] = creg;   // c_t
          Ys[r * HS + colc] = LW[colc] * hreg;   // y partials
        }
      }
      __syncthreads();

      if (t < T_STEPS - 1 && lrow < ROWS) {      // h i8 fragments for t+1
        const unsigned char* hb = &Hq[(t + 1) & 1][lrow * HROW];
        afr[0] = *(const i32x4*)&hb[lg << 4];
        afr[1] = *(const i32x4*)&hb[64 + (lg << 4)];
      }
    }
  }

  // ---- y = h @ linear_w.T + b ----
  if (tid < 8) {
    const int r = tid >> 2, seg = tid & 3;
    float s = 0.f;
#pragma unroll 8
    for (int j = 0; j < 32; ++j) s += Ys[r * 128 + seg * 32 + j];
    Ps[tid] = s;
  }
  __syncthreads();
  if (tid < ROWS) {
    OUT[blk * ROWS + tid] = LB[0] + Ps[tid * 4] + Ps[tid * 4 + 1]
                                  + Ps[tid * 4 + 2] + Ps[tid * 4 + 3];
  }
}

extern "C" void kernel_launch(void* const* d_in, const int* in_sizes, int n_in,
                              void* d_out, int out_size, void* d_ws, size_t ws_size,
                              hipStream_t stream) {
  const float* X  = (const float*)d_in[0];
  const float* W  = (const float*)d_in[1];
  const float* U  = (const float*)d_in[2];
  const float* B  = (const float*)d_in[3];
  const float* LW = (const float*)d_in[4];
  const float* LB = (const float*)d_in[5];
  lstm_fused<<<dim3(NBLK), dim3(NTHR), 0, stream>>>(X, W, U, B, LW, LB, (float*)d_out);
}

// Round 16
// 1033.569 us; speedup vs baseline: 1.9606x; 1.0214x over previous
//
#include <hip/hip_runtime.h>

// LSTM BS=512, T=2048, IN=64, HS=128.  Single fused persistent kernel.
// R15 base (1056us): 256 blocks x 2 rows, 8 waves; bf16 chunk GEMM (Z=x@W+b)
// from LDS-staged x (T14); scan = i8 MFMA U*h (mfma_i32_16x16x64_i8).
// R16 epilogue restructure:
//  - h rows live in A-slots {0,4} -> lane-group lg in {0,1} reads its row
//    from acc[n][0] directly (no ds_swizzle, no selects).
//  - activations dense across 64 lanes: lanes 0-31 do (i,g), lanes 32-63 do
//    (f,o)+cell update; gates shipped via 3 ds_bpermute (R11-verified).
//    sigm/tanh unified as cB*rcp(1+exp(cA*x))+cC -> 3 exp + 3 rcp per step.

#define T_STEPS 2048
#define IN_DIM 64
#define HS 128
#define NG 512
#define ROWS 2
#define NBLK 256
#define NTHR 512
#define CH 32
#define NCH (T_STEPS / CH)
#define HROW 144   // bytes per h slot (128 + 16 pad)

typedef float f32x4 __attribute__((ext_vector_type(4)));
typedef short s16x8 __attribute__((ext_vector_type(8)));
typedef int   i32x4 __attribute__((ext_vector_type(4)));

__device__ __forceinline__ unsigned f2bf(float f) {
  unsigned u = __float_as_uint(f);
  return (u + 0x7fffu + ((u >> 16) & 1u)) >> 16;  // RNE
}
__device__ __forceinline__ float rcpf(float x) { return __builtin_amdgcn_rcpf(x); }
__device__ __forceinline__ float tanhfast(float x) {
  return 1.0f - 2.0f * rcpf(__expf(2.0f * x) + 1.0f);  // exact at +-inf
}
// Xl float-index swizzle: XOR t' (bits 7..9) into the 8-float granule bits
__device__ __forceinline__ int xswz(int f) { return f ^ (((f >> 7) & 7) << 3); }

__global__ __launch_bounds__(NTHR, 1)
void lstm_fused(const float* __restrict__ X, const float* __restrict__ W,
                const float* __restrict__ U, const float* __restrict__ B,
                const float* __restrict__ LW, const float* __restrict__ LB,
                float* __restrict__ OUT) {
  __shared__ __align__(16) short Zc[CH * 128 * 8];       // 64 KB gates bf16
  __shared__ __align__(16) float Xl[4096];               // 16 KB x-tile
  __shared__ __align__(16) unsigned char Hq[2][2][HROW]; // h i8, slots {0,4}
  __shared__ float Ys[256];
  __shared__ float Ps[8];

  const int tid  = threadIdx.x;
  const int lane = tid & 63;
  const int w    = tid >> 6;
  const int blk  = blockIdx.x;
  const int lrow = lane & 15;
  const int lg   = lane >> 4;
  const int col8 = (w * 16 + lrow) * 8;     // Zc cell offset (shorts)
  const bool low = (lane < 32);
  const int bidx = (lane & 31) << 2;        // bpermute byte index

  // ---- U: per-column i8 quantization; wave w owns col p = n*128+16w+lrow
  // B-frag (mfma_i32_16x16x64_i8): B[k][p], k = kt*64 + 16*lg + j
  i32x4 bUq[4][2];
  float scl[4];
  s16x8 bfrW[4][2];
  float biasg[4];
#pragma unroll
  for (int n = 0; n < 4; ++n) {
    const int p = n * HS + w * 16 + lrow;
    float m = 1e-8f;
    for (int k = 0; k < HS; ++k) m = fmaxf(m, fabsf(U[k * NG + p]));
    const float rsu = 127.f / m;
    scl[n] = m / (127.f * 127.f);
#pragma unroll
    for (int kt = 0; kt < 2; ++kt) {
      int vq[4] = {0, 0, 0, 0};
      for (int j = 0; j < 16; ++j) {
        const int k = kt * 64 + (lg << 4) + j;
        int q = (int)rintf(U[k * NG + p] * rsu);
        q = q < -127 ? -127 : (q > 127 ? 127 : q);
        vq[j >> 2] |= (q & 0xff) << ((j & 3) * 8);
      }
      bUq[n][kt] = (i32x4){vq[0], vq[1], vq[2], vq[3]};
    }
#pragma unroll
    for (int kt = 0; kt < 2; ++kt)
#pragma unroll
      for (int j = 0; j < 8; ++j)
        bfrW[n][kt][j] = (short)f2bf(W[(kt * 32 + (lg << 3) + j) * NG + p]);
    biasg[n] = B[p];
  }
  // per-lane activation constants: low lanes: A=(i:sigm), B=(g:tanh);
  // high lanes: A=(f:sigm), B=(o:sigm).  y = cB*rcp(1+exp(cA*x)) + cC.
  const float sA = low ? scl[0] : scl[1];
  const float sB = low ? scl[2] : scl[3];
  const float cA = low ? -2.f : -1.f;   // for gate B only
  const float cB = low ?  2.f :  1.f;
  const float cC = low ? -1.f :  0.f;

  // ---- x staging (T14 split): waves 0..3 own m-tile w of the chunk ----
  f32x4 sx0, sx1, sx2, sx3;
  auto stage_load = [&](int cc) {
    if (w < 4) {
#pragma unroll
      for (int q = 0; q < 4; ++q) {
        const int f   = w * 1024 + q * 256 + lane * 4;
        const int tlc = f >> 7;
        const int row = (f >> 6) & 1;
        const int k   = f & 63;
        const f32x4 v = *(const f32x4*)(
            X + ((long)(blk * ROWS + row) * T_STEPS + (long)cc * CH + tlc) * IN_DIM + k);
        if (q == 0) sx0 = v; else if (q == 1) sx1 = v;
        else if (q == 2) sx2 = v; else sx3 = v;
      }
    }
  };
  auto stage_write = [&]() {
    if (w < 4) {
#pragma unroll
      for (int q = 0; q < 4; ++q) {
        const int f = w * 1024 + q * 256 + lane * 4;
        const f32x4 v = (q == 0) ? sx0 : (q == 1) ? sx1 : (q == 2) ? sx2 : sx3;
        *(f32x4*)&Xl[xswz(f)] = v;
      }
    }
  };

  stage_load(0);
  stage_write();
  for (int i = tid; i < 2 * 2 * HROW; i += NTHR) ((unsigned char*)Hq)[i] = 0;

  i32x4 afr[2];
  const i32x4 izer = {0, 0, 0, 0};
  afr[0] = izer; afr[1] = izer;   // h(0) = 0 (inactive lanes keep zero forever)

  float creg = 0.f, hreg = 0.f;   // cell state lives on lanes 32..63
  __syncthreads();

#pragma unroll 1
  for (int c = 0; c < NCH; ++c) {
    // ===== chunk GEMM: Zc = x@W + bias, x from LDS (bf16, unchanged) ======
#pragma unroll
    for (int mt = 0; mt < 4; ++mt) {
      const int fb = mt * 1024 + (lrow >> 1) * 128 + (lrow & 1) * 64;
      const int f0 = xswz(fb + 8 * lg);
      const int f1 = xswz(fb + 32 + 8 * lg);
      const f32x4 x0 = *(const f32x4*)&Xl[f0];
      const f32x4 x1 = *(const f32x4*)&Xl[f0 + 4];
      const f32x4 x2 = *(const f32x4*)&Xl[f1];
      const f32x4 x3 = *(const f32x4*)&Xl[f1 + 4];
      s16x8 a0, a1;
#pragma unroll
      for (int j = 0; j < 4; ++j) {
        a0[j] = (short)f2bf(x0[j]); a0[4 + j] = (short)f2bf(x1[j]);
        a1[j] = (short)f2bf(x2[j]); a1[4 + j] = (short)f2bf(x3[j]);
      }
      f32x4 ac[4];
#pragma unroll
      for (int n = 0; n < 4; ++n) {
        ac[n][0] = biasg[n]; ac[n][1] = biasg[n];
        ac[n][2] = biasg[n]; ac[n][3] = biasg[n];
      }
#pragma unroll
      for (int n = 0; n < 4; ++n)
        ac[n] = __builtin_amdgcn_mfma_f32_16x16x32_bf16(a0, bfrW[n][0], ac[n], 0, 0, 0);
#pragma unroll
      for (int n = 0; n < 4; ++n)
        ac[n] = __builtin_amdgcn_mfma_f32_16x16x32_bf16(a1, bfrW[n][1], ac[n], 0, 0, 0);
      s16x8 z0, z1;
#pragma unroll
      for (int n = 0; n < 4; ++n) {
        z0[n] = (short)f2bf(ac[n][0]); z0[4 + n] = (short)f2bf(ac[n][1]);
        z1[n] = (short)f2bf(ac[n][2]); z1[4 + n] = (short)f2bf(ac[n][3]);
      }
      const int tl0 = mt * 8 + 2 * lg;
      *(s16x8*)&Zc[tl0 * 1024 + col8]       = z0;
      *(s16x8*)&Zc[(tl0 + 1) * 1024 + col8] = z1;
    }
    __syncthreads();
    stage_load((c + 1 < NCH) ? c + 1 : c);

    // ===== 32 scan steps ==================================================
#pragma unroll 1
    for (int tl = 0; tl < CH; ++tl) {
      const int t = c * CH + tl;
      // per-lane cell z: shorts [i,f,g,o] of (r = lg&1, col)
      const uint2 zu = *(const uint2*)&Zc[tl * 1024 + col8 + (lg & 1) * 4];

      i32x4 acc[4];
#pragma unroll
      for (int n = 0; n < 4; ++n) acc[n] = izer;

      // order {1,3,0,2}: f,o accs retire first (they feed the bpermutes)
      __builtin_amdgcn_s_setprio(1);
#pragma unroll
      for (int kt = 0; kt < 2; ++kt) {
        acc[1] = __builtin_amdgcn_mfma_i32_16x16x64_i8(afr[kt], bUq[1][kt], acc[1], 0, 0, 0);
        acc[3] = __builtin_amdgcn_mfma_i32_16x16x64_i8(afr[kt], bUq[3][kt], acc[3], 0, 0, 0);
        acc[0] = __builtin_amdgcn_mfma_i32_16x16x64_i8(afr[kt], bUq[0][kt], acc[0], 0, 0, 0);
        acc[2] = __builtin_amdgcn_mfma_i32_16x16x64_i8(afr[kt], bUq[2][kt], acc[2], 0, 0, 0);
      }
      __builtin_amdgcn_s_setprio(0);

      if (tl == 4) stage_write();

      // ship f,o raw accs to upper lanes; dense dual-gate activation
      const int r1 = __builtin_amdgcn_ds_bpermute(bidx, acc[1][0]);
      const int r3 = __builtin_amdgcn_ds_bpermute(bidx, acc[3][0]);
      const int a02 = low ? acc[0][0] : r1;    // i | f (raw i32)
      const int a13 = low ? acc[2][0] : r3;    // g | o
      const float zA = __int_as_float(low ? (zu.x << 16) : (zu.x & 0xffff0000u));
      const float zB = __int_as_float(low ? (zu.y << 16) : (zu.y & 0xffff0000u));
      const float vA = (float)a02 * sA + zA;
      const float vB = (float)a13 * sB + zB;
      const float g1 = rcpf(1.f + __expf(-vA));            // iv | fv
      const float g2 = cB * rcpf(1.f + __expf(cA * vB)) + cC;  // gv | ov
      const float pg = g1 * g2;                            // i*g on low lanes
      const float pgp = __int_as_float(
          __builtin_amdgcn_ds_bpermute(bidx, __float_as_int(pg)));
      creg = g1 * creg + pgp;          // upper: f*c + i*g (lower: garbage, unused)
      const float tc = tanhfast(creg);
      hreg = g2 * tc;                  // upper: o * tanh(c)

      if (lane >= 32) {
        const int b    = lane - 32;
        const int colc = w * 16 + (b & 15);
        const int r    = b >> 4;
        if (t < T_STEPS - 1) {
          const int hq = (int)rintf(hreg * 127.f);
          Hq[(t + 1) & 1][r][colc] = (unsigned char)hq;
        } else {
          const int row = blk * ROWS + r;
          OUT[512 + row * HS + colc]   = hreg;   // h_t
          OUT[66048 + row * HS + colc] = creg;   // c_t
          Ys[r * HS + colc] = LW[colc] * hreg;   // y partials
        }
      }
      __syncthreads();

      // h i8 fragments for t+1: rows live in A-slots {0,4}
      if (t < T_STEPS - 1 && (lrow & 3) == 0 && lrow < 8) {
        const unsigned char* hb = Hq[(t + 1) & 1][lrow >> 2];
        afr[0] = *(const i32x4*)&hb[lg << 4];
        afr[1] = *(const i32x4*)&hb[64 + (lg << 4)];
      }
    }
  }

  // ---- y = h @ linear_w.T + b ----
  if (tid < 8) {
    const int r = tid >> 2, seg = tid & 3;
    float s = 0.f;
#pragma unroll 8
    for (int j = 0; j < 32; ++j) s += Ys[r * 128 + seg * 32 + j];
    Ps[tid] = s;
  }
  __syncthreads();
  if (tid < ROWS) {
    OUT[blk * ROWS + tid] = LB[0] + Ps[tid * 4] + Ps[tid * 4 + 1]
                                  + Ps[tid * 4 + 2] + Ps[tid * 4 + 3];
  }
}

extern "C" void kernel_launch(void* const* d_in, const int* in_sizes, int n_in,
                              void* d_out, int out_size, void* d_ws, size_t ws_size,
                              hipStream_t stream) {
  const float* X  = (const float*)d_in[0];
  const float* W  = (const float*)d_in[1];
  const float* U  = (const float*)d_in[2];
  const float* B  = (const float*)d_in[3];
  const float* LW = (const float*)d_in[4];
  const float* LB = (const float*)d_in[5];
  lstm_fused<<<dim3(NBLK), dim3(NTHR), 0, stream>>>(X, W, U, B, LW, LB, (float*)d_out);
}

// Round 17
// 931.103 us; speedup vs baseline: 2.1764x; 1.1100x over previous
//
#include <hip/hip_runtime.h>

// LSTM BS=512, T=2048, IN=64, HS=128.  Single fused persistent kernel.
// 256 blocks x 2 rows, 8 waves; bf16 chunk GEMM (Z=x@W+b) from LDS-staged x
// (T14 split); scan = i8 MFMA U*h (mfma_i32_16x16x64_i8), h rows in A-slots
// {0,4}.
// R17: epilogue is fully LANE-LOCAL. Because D-row = 4*lg + reg, lanes 0-15
// (lg=0) hold row0's 4 gate accs in acc[n][0] and lanes 16-31 (lg=1) hold
// row1's. Each lane dequants its 4 gates, updates its cell, writes 1 h byte.
// Zero cross-lane ops in the critical chain (R16 had 2 serial bpermutes).

#define T_STEPS 2048
#define IN_DIM 64
#define HS 128
#define NG 512
#define ROWS 2
#define NBLK 256
#define NTHR 512
#define CH 32
#define NCH (T_STEPS / CH)
#define HROW 144   // bytes per h slot (128 + 16 pad)

typedef float f32x4 __attribute__((ext_vector_type(4)));
typedef short s16x8 __attribute__((ext_vector_type(8)));
typedef int   i32x4 __attribute__((ext_vector_type(4)));

__device__ __forceinline__ unsigned f2bf(float f) {
  unsigned u = __float_as_uint(f);
  return (u + 0x7fffu + ((u >> 16) & 1u)) >> 16;  // RNE
}
__device__ __forceinline__ float bf2f(unsigned short s) {
  return __int_as_float(((int)s) << 16);
}
__device__ __forceinline__ float rcpf(float x) { return __builtin_amdgcn_rcpf(x); }
__device__ __forceinline__ float sigm(float x) { return rcpf(1.f + __expf(-x)); }
__device__ __forceinline__ float tanhfast(float x) {
  return 1.0f - 2.0f * rcpf(__expf(2.0f * x) + 1.0f);  // exact at +-inf
}
// Xl float-index swizzle: XOR t' (bits 7..9) into the 8-float granule bits
__device__ __forceinline__ int xswz(int f) { return f ^ (((f >> 7) & 7) << 3); }

__global__ __launch_bounds__(NTHR, 1)
void lstm_fused(const float* __restrict__ X, const float* __restrict__ W,
                const float* __restrict__ U, const float* __restrict__ B,
                const float* __restrict__ LW, const float* __restrict__ LB,
                float* __restrict__ OUT) {
  __shared__ __align__(16) short Zc[CH * 128 * 8];       // 64 KB gates bf16
  __shared__ __align__(16) float Xl[4096];               // 16 KB x-tile
  __shared__ __align__(16) unsigned char Hq[2][2][HROW]; // h i8, slots {0,4}
  __shared__ float Ys[256];
  __shared__ float Ps[8];

  const int tid  = threadIdx.x;
  const int lane = tid & 63;
  const int w    = tid >> 6;
  const int blk  = blockIdx.x;
  const int lrow = lane & 15;
  const int lg   = lane >> 4;
  const int col8 = (w * 16 + lrow) * 8;     // Zc cell offset (shorts)

  // ---- U: per-column i8 quantization; wave w owns col p = n*128+16w+lrow
  // B-frag (mfma_i32_16x16x64_i8): B[k][p], k = kt*64 + 16*lg + j
  i32x4 bUq[4][2];
  float scl[4];
  s16x8 bfrW[4][2];
  float biasg[4];
#pragma unroll
  for (int n = 0; n < 4; ++n) {
    const int p = n * HS + w * 16 + lrow;
    float m = 1e-8f;
    for (int k = 0; k < HS; ++k) m = fmaxf(m, fabsf(U[k * NG + p]));
    const float rsu = 127.f / m;
    scl[n] = m / (127.f * 127.f);
#pragma unroll
    for (int kt = 0; kt < 2; ++kt) {
      int vq[4] = {0, 0, 0, 0};
      for (int j = 0; j < 16; ++j) {
        const int k = kt * 64 + (lg << 4) + j;
        int q = (int)rintf(U[k * NG + p] * rsu);
        q = q < -127 ? -127 : (q > 127 ? 127 : q);
        vq[j >> 2] |= (q & 0xff) << ((j & 3) * 8);
      }
      bUq[n][kt] = (i32x4){vq[0], vq[1], vq[2], vq[3]};
    }
#pragma unroll
    for (int kt = 0; kt < 2; ++kt)
#pragma unroll
      for (int j = 0; j < 8; ++j)
        bfrW[n][kt][j] = (short)f2bf(W[(kt * 32 + (lg << 3) + j) * NG + p]);
    biasg[n] = B[p];
  }

  // ---- x staging (T14 split): waves 0..3 own m-tile w of the chunk ----
  f32x4 sx0, sx1, sx2, sx3;
  auto stage_load = [&](int cc) {
    if (w < 4) {
#pragma unroll
      for (int q = 0; q < 4; ++q) {
        const int f   = w * 1024 + q * 256 + lane * 4;
        const int tlc = f >> 7;
        const int row = (f >> 6) & 1;
        const int k   = f & 63;
        const f32x4 v = *(const f32x4*)(
            X + ((long)(blk * ROWS + row) * T_STEPS + (long)cc * CH + tlc) * IN_DIM + k);
        if (q == 0) sx0 = v; else if (q == 1) sx1 = v;
        else if (q == 2) sx2 = v; else sx3 = v;
      }
    }
  };
  auto stage_write = [&]() {
    if (w < 4) {
#pragma unroll
      for (int q = 0; q < 4; ++q) {
        const int f = w * 1024 + q * 256 + lane * 4;
        const f32x4 v = (q == 0) ? sx0 : (q == 1) ? sx1 : (q == 2) ? sx2 : sx3;
        *(f32x4*)&Xl[xswz(f)] = v;
      }
    }
  };

  stage_load(0);
  stage_write();
  for (int i = tid; i < 2 * 2 * HROW; i += NTHR) ((unsigned char*)Hq)[i] = 0;

  i32x4 afr[2];
  const i32x4 izer = {0, 0, 0, 0};
  afr[0] = izer; afr[1] = izer;   // h(0) = 0 (non-loader lanes keep zero)

  float creg = 0.f, hreg = 0.f;   // cell state lives on lanes 0..31
  __syncthreads();

#pragma unroll 1
  for (int c = 0; c < NCH; ++c) {
    // ===== chunk GEMM: Zc = x@W + bias, x from LDS (bf16, unchanged) ======
#pragma unroll
    for (int mt = 0; mt < 4; ++mt) {
      const int fb = mt * 1024 + (lrow >> 1) * 128 + (lrow & 1) * 64;
      const int f0 = xswz(fb + 8 * lg);
      const int f1 = xswz(fb + 32 + 8 * lg);
      const f32x4 x0 = *(const f32x4*)&Xl[f0];
      const f32x4 x1 = *(const f32x4*)&Xl[f0 + 4];
      const f32x4 x2 = *(const f32x4*)&Xl[f1];
      const f32x4 x3 = *(const f32x4*)&Xl[f1 + 4];
      s16x8 a0, a1;
#pragma unroll
      for (int j = 0; j < 4; ++j) {
        a0[j] = (short)f2bf(x0[j]); a0[4 + j] = (short)f2bf(x1[j]);
        a1[j] = (short)f2bf(x2[j]); a1[4 + j] = (short)f2bf(x3[j]);
      }
      f32x4 ac[4];
#pragma unroll
      for (int n = 0; n < 4; ++n) {
        ac[n][0] = biasg[n]; ac[n][1] = biasg[n];
        ac[n][2] = biasg[n]; ac[n][3] = biasg[n];
      }
#pragma unroll
      for (int n = 0; n < 4; ++n)
        ac[n] = __builtin_amdgcn_mfma_f32_16x16x32_bf16(a0, bfrW[n][0], ac[n], 0, 0, 0);
#pragma unroll
      for (int n = 0; n < 4; ++n)
        ac[n] = __builtin_amdgcn_mfma_f32_16x16x32_bf16(a1, bfrW[n][1], ac[n], 0, 0, 0);
      s16x8 z0, z1;
#pragma unroll
      for (int n = 0; n < 4; ++n) {
        z0[n] = (short)f2bf(ac[n][0]); z0[4 + n] = (short)f2bf(ac[n][1]);
        z1[n] = (short)f2bf(ac[n][2]); z1[4 + n] = (short)f2bf(ac[n][3]);
      }
      const int tl0 = mt * 8 + 2 * lg;
      *(s16x8*)&Zc[tl0 * 1024 + col8]       = z0;
      *(s16x8*)&Zc[(tl0 + 1) * 1024 + col8] = z1;
    }
    __syncthreads();
    stage_load((c + 1 < NCH) ? c + 1 : c);

    // ===== 32 scan steps: i8 MFMA; fully lane-local epilogue ==============
#pragma unroll 1
    for (int tl = 0; tl < CH; ++tl) {
      const int t = c * CH + tl;
      // lane's cell z: 4 shorts [i,f,g,o] of (row = lg&1, col)
      const uint2 zu = *(const uint2*)&Zc[tl * 1024 + col8 + (lg & 1) * 4];

      i32x4 acc[4];
#pragma unroll
      for (int n = 0; n < 4; ++n) acc[n] = izer;

      __builtin_amdgcn_s_setprio(1);
#pragma unroll
      for (int kt = 0; kt < 2; ++kt) {
        acc[0] = __builtin_amdgcn_mfma_i32_16x16x64_i8(afr[kt], bUq[0][kt], acc[0], 0, 0, 0);
        acc[1] = __builtin_amdgcn_mfma_i32_16x16x64_i8(afr[kt], bUq[1][kt], acc[1], 0, 0, 0);
        acc[2] = __builtin_amdgcn_mfma_i32_16x16x64_i8(afr[kt], bUq[2][kt], acc[2], 0, 0, 0);
        acc[3] = __builtin_amdgcn_mfma_i32_16x16x64_i8(afr[kt], bUq[3][kt], acc[3], 0, 0, 0);
      }
      __builtin_amdgcn_s_setprio(0);

      if (tl == 4) stage_write();

      // lanes 0-31: acc[n][0] is THIS lane's cell's gate n (D-row 4*lg).
      if (lane < 32) {
        const float v0 = (float)acc[0][0] * scl[0] + bf2f((unsigned short)(zu.x & 0xffff));
        const float v1 = (float)acc[1][0] * scl[1] + bf2f((unsigned short)(zu.x >> 16));
        const float v2 = (float)acc[2][0] * scl[2] + bf2f((unsigned short)(zu.y & 0xffff));
        const float v3 = (float)acc[3][0] * scl[3] + bf2f((unsigned short)(zu.y >> 16));
        const float iv = sigm(v0), fv = sigm(v1);
        const float gv = tanhfast(v2), ov = sigm(v3);
        creg = fv * creg + iv * gv;
        hreg = ov * tanhfast(creg);
        const int colc = w * 16 + lrow;
        const int r    = lg;                 // 0 or 1
        if (t < T_STEPS - 1) {
          const int hq = (int)rintf(hreg * 127.f);
          Hq[(t + 1) & 1][r][colc] = (unsigned char)hq;
        } else {
          const int row = blk * ROWS + r;
          OUT[512 + row * HS + colc]   = hreg;   // h_t
          OUT[66048 + row * HS + colc] = creg;   // c_t
          Ys[r * HS + colc] = LW[colc] * hreg;   // y partials
        }
      }
      __syncthreads();

      // h i8 fragments for t+1: rows live in A-slots {0,4}
      if (t < T_STEPS - 1 && (lrow & 3) == 0 && lrow < 8) {
        const unsigned char* hb = Hq[(t + 1) & 1][lrow >> 2];
        afr[0] = *(const i32x4*)&hb[lg << 4];
        afr[1] = *(const i32x4*)&hb[64 + (lg << 4)];
      }
    }
  }

  // ---- y = h @ linear_w.T + b ----
  if (tid < 8) {
    const int r = tid >> 2, seg = tid & 3;
    float s = 0.f;
#pragma unroll 8
    for (int j = 0; j < 32; ++j) s += Ys[r * 128 + seg * 32 + j];
    Ps[tid] = s;
  }
  __syncthreads();
  if (tid < ROWS) {
    OUT[blk * ROWS + tid] = LB[0] + Ps[tid * 4] + Ps[tid * 4 + 1]
                                  + Ps[tid * 4 + 2] + Ps[tid * 4 + 3];
  }
}

extern "C" void kernel_launch(void* const* d_in, const int* in_sizes, int n_in,
                              void* d_out, int out_size, void* d_ws, size_t ws_size,
                              hipStream_t stream) {
  const float* X  = (const float*)d_in[0];
  const float* W  = (const float*)d_in[1];
  const float* U  = (const float*)d_in[2];
  const float* B  = (const float*)d_in[3];
  const float* LW = (const float*)d_in[4];
  const float* LB = (const float*)d_in[5];
  lstm_fused<<<dim3(NBLK), dim3(NTHR), 0, stream>>>(X, W, U, B, LW, LB, (float*)d_out);
}